// Round 1
// baseline (516.055 us; speedup 1.0000x reference)
//
#include <hip/hip_runtime.h>

typedef __bf16 bf16_t;
typedef __bf16 bf16x8 __attribute__((ext_vector_type(8)));
typedef __bf16 bf16x4 __attribute__((ext_vector_type(4)));
typedef float f32x4 __attribute__((ext_vector_type(4)));

#define MFMA16(a, b, c) __builtin_amdgcn_mfma_f32_16x16x32_bf16(a, b, c, 0, 0, 0)

__device__ __forceinline__ void g2l16(const void* g, void* l) {
  __builtin_amdgcn_global_load_lds(
      (__attribute__((address_space(1))) void*)g,
      (__attribute__((address_space(3))) void*)l, 16, 0, 0);
}

// ---------------- fp32 -> bf16 conversion ----------------
__global__ void cvt_f32_bf16(const float* __restrict__ in, bf16_t* __restrict__ out, int n4) {
  int i = blockIdx.x * blockDim.x + threadIdx.x;
  if (i >= n4) return;
  const float4 v = ((const float4*)in)[i];
  bf16x4 o;
  o[0] = (bf16_t)v.x; o[1] = (bf16_t)v.y; o[2] = (bf16_t)v.z; o[3] = (bf16_t)v.w;
  ((bf16x4*)out)[i] = o;
}

// ---------------- NT GEMM: C[m][n] = sum_k A[m][k] * B[n][k]  ----------------
// MODE 0: QKV epilogue (add bqkv, scatter to Q(scaled)/K/V^T bf16 buffers)
// MODE 1: proj epilogue (add bproj, fp32 store to Cout)
template <int MODE>
__global__ __launch_bounds__(256, 2) void gemm_bt(
    const bf16_t* __restrict__ A, const bf16_t* __restrict__ Bw,
    const float* __restrict__ bias, float* __restrict__ Cout,
    bf16_t* __restrict__ Qb, bf16_t* __restrict__ Kb, bf16_t* __restrict__ Vtb,
    int M, int N, int K) {
  __shared__ bf16_t As[128 * 32];
  __shared__ bf16_t Bs[128 * 32];
  const int tid = threadIdx.x;
  const int wave = tid >> 6, lane = tid & 63, quad = lane >> 4, lr = lane & 15;
  const int bm = blockIdx.x * 128, bn = blockIdx.y * 128;
  const int wm = (wave >> 1) * 64, wn = (wave & 1) * 64;

  f32x4 acc[4][4] = {};

  const bf16_t* Ag = A + (size_t)(bm + (tid >> 2)) * K + (tid & 3) * 8;
  const bf16_t* Bg = Bw + (size_t)(bn + (tid >> 2)) * K + (tid & 3) * 8;
  bf16_t* As0 = As + tid * 8;
  bf16_t* Bs0 = Bs + tid * 8;
  const size_t stride64 = (size_t)64 * K;

  for (int k0 = 0; k0 < K; k0 += 32) {
    __syncthreads();
    g2l16(Ag + k0, As0);
    g2l16(Ag + stride64 + k0, As0 + 2048);
    g2l16(Bg + k0, Bs0);
    g2l16(Bg + stride64 + k0, Bs0 + 2048);
    __syncthreads();
    bf16x8 af[4], bfr[4];
#pragma unroll
    for (int i = 0; i < 4; ++i)
      af[i] = *(const bf16x8*)(As + (wm + i * 16 + lr) * 32 + quad * 8);
#pragma unroll
    for (int j = 0; j < 4; ++j)
      bfr[j] = *(const bf16x8*)(Bs + (wn + j * 16 + lr) * 32 + quad * 8);
#pragma unroll
    for (int i = 0; i < 4; ++i)
#pragma unroll
      for (int j = 0; j < 4; ++j)
        acc[i][j] = MFMA16(af[i], bfr[j], acc[i][j]);
  }

#pragma unroll
  for (int i = 0; i < 4; ++i) {
    const int row = bm + wm + i * 16 + quad * 4;
#pragma unroll
    for (int j = 0; j < 4; ++j) {
      const int col = bn + wn + j * 16 + lr;
      const float bb = bias[col];
#pragma unroll
      for (int r = 0; r < 4; ++r) {
        const float v = acc[i][j][r] + bb;
        const int rr = row + r;
        if (MODE == 1) {
          Cout[(size_t)rr * N + col] = v;
        } else {
          const int b = rr >> 10, seq = rr & 1023;
          const int head = col / 96, w = col % 96;
          const int bh = b * 24 + head;
          if (w < 32) {
            Qb[((size_t)bh * 1024 + seq) * 32 + w] = (bf16_t)(v * 0.17677669529663687f);
          } else if (w < 64) {
            Kb[((size_t)bh * 1024 + seq) * 32 + (w - 32)] = (bf16_t)v;
          } else {
            Vtb[((size_t)bh * 32 + (w - 64)) * 1024 + seq] = (bf16_t)v;
          }
        }
      }
    }
  }
}

// ---------------- flash attention ----------------
// grid: x = q-tile (16 tiles of 64), y = b*24+h (192). 4 waves, wave = 16 q rows.
__global__ __launch_bounds__(256, 2) void attn_flash(
    const bf16_t* __restrict__ Qb, const bf16_t* __restrict__ Kb,
    const bf16_t* __restrict__ Vtb, const float* __restrict__ rel,
    bf16_t* __restrict__ Ob) {
  __shared__ bf16_t Ks[128 * 32];
  __shared__ bf16_t Vs[32 * 136];      // V^T tile, padded stride 136
  __shared__ bf16_t Ps[4][16 * 136];   // per-wave P scratch, padded

  const int tid = threadIdx.x;
  const int wave = tid >> 6, lane = tid & 63, quad = lane >> 4, lr = lane & 15;
  const int bh = blockIdx.y;
  const int h = bh % 24, b = bh / 24;
  const int q0 = blockIdx.x * 64 + wave * 16;

  const bf16x8 qf = *(const bf16x8*)(Qb + ((size_t)bh * 1024 + q0 + lr) * 32 + quad * 8);

  f32x4 o_acc[2] = {};
  float m_i[4], l_i[4];
#pragma unroll
  for (int r = 0; r < 4; ++r) { m_i[r] = -1e30f; l_i[r] = 0.0f; }

  const bf16_t* Kg = Kb + ((size_t)bh * 1024 + (tid >> 2)) * 32 + (tid & 3) * 8;
  const int vr = tid >> 4, vc = (tid & 15) * 8;
  const bf16_t* Vg = Vtb + ((size_t)bh * 32 + vr) * 1024 + vc;
  const float* relg = rel + ((size_t)h * 1024 + q0 + quad * 4) * 1024 + lr;
  bf16_t* Pw = &Ps[wave][0];
  const float LOG2E = 1.44269504f;

  for (int kt = 0; kt < 1024; kt += 128) {
    __syncthreads();
    g2l16(Kg + (size_t)kt * 32, Ks + tid * 8);
    g2l16(Kg + (size_t)kt * 32 + 64 * 32, Ks + tid * 8 + 2048);
    const uint4 v0 = *(const uint4*)(Vg + kt);
    const uint4 v1 = *(const uint4*)(Vg + 16 * 1024 + kt);
    *(uint4*)(Vs + vr * 136 + vc) = v0;
    *(uint4*)(Vs + (vr + 16) * 136 + vc) = v1;
    __syncthreads();

    // S = Q K^T + bias   (16 x 128, C-layout: row = quad*4+r, col = jt*16+lr)
    f32x4 s[8];
    const f32x4 zz = {0.f, 0.f, 0.f, 0.f};
#pragma unroll
    for (int jt = 0; jt < 8; ++jt) {
      bf16x8 kf = *(const bf16x8*)(Ks + (jt * 16 + lr) * 32 + quad * 8);
      s[jt] = MFMA16(qf, kf, zz);
    }
    const float* rb = relg + kt;
#pragma unroll
    for (int jt = 0; jt < 8; ++jt)
#pragma unroll
      for (int r = 0; r < 4; ++r)
        s[jt][r] += rb[(size_t)r * 1024 + jt * 16];

    // online softmax over the 128 new columns
    float alpha[4];
#pragma unroll
    for (int r = 0; r < 4; ++r) {
      float mx = s[0][r];
#pragma unroll
      for (int jt = 1; jt < 8; ++jt) mx = fmaxf(mx, s[jt][r]);
#pragma unroll
      for (int off = 1; off < 16; off <<= 1) mx = fmaxf(mx, __shfl_xor(mx, off, 16));
      const float mn = fmaxf(m_i[r], mx);
      alpha[r] = exp2f((m_i[r] - mn) * LOG2E);
      m_i[r] = mn;
    }
#pragma unroll
    for (int jt = 0; jt < 8; ++jt)
#pragma unroll
      for (int r = 0; r < 4; ++r)
        s[jt][r] = exp2f((s[jt][r] - m_i[r]) * LOG2E);
#pragma unroll
    for (int r = 0; r < 4; ++r) {
      float sm = 0.f;
#pragma unroll
      for (int jt = 0; jt < 8; ++jt) sm += s[jt][r];
#pragma unroll
      for (int off = 1; off < 16; off <<= 1) sm += __shfl_xor(sm, off, 16);
      l_i[r] = l_i[r] * alpha[r] + sm;
    }
#pragma unroll
    for (int nt = 0; nt < 2; ++nt)
#pragma unroll
      for (int r = 0; r < 4; ++r) o_acc[nt][r] *= alpha[r];

    // P (C-layout) -> LDS -> A-layout for PV
#pragma unroll
    for (int jt = 0; jt < 8; ++jt)
#pragma unroll
      for (int r = 0; r < 4; ++r)
        Pw[(quad * 4 + r) * 136 + jt * 16 + lr] = (bf16_t)s[jt][r];

    // O += P V   (2 n-tiles of 16, 4 k-steps of 32)
#pragma unroll
    for (int ks = 0; ks < 4; ++ks) {
      bf16x8 pf = *(const bf16x8*)(Pw + lr * 136 + ks * 32 + quad * 8);
#pragma unroll
      for (int nt = 0; nt < 2; ++nt) {
        bf16x8 vf = *(const bf16x8*)(Vs + (nt * 16 + lr) * 136 + ks * 32 + quad * 8);
        o_acc[nt] = MFMA16(pf, vf, o_acc[nt]);
      }
    }
  }

  // write O / l  as bf16 into [B, N, H*32]
#pragma unroll
  for (int nt = 0; nt < 2; ++nt)
#pragma unroll
    for (int r = 0; r < 4; ++r) {
      const int seq = q0 + quad * 4 + r;
      const float ov = o_acc[nt][r] / l_i[r];
      Ob[((size_t)b * 1024 + seq) * 768 + h * 32 + nt * 16 + lr] = (bf16_t)ov;
    }
}

extern "C" void kernel_launch(void* const* d_in, const int* in_sizes, int n_in,
                              void* d_out, int out_size, void* d_ws, size_t ws_size,
                              hipStream_t stream) {
  const float* x = (const float*)d_in[0];
  const float* rel = (const float*)d_in[1];
  const float* Wqkv = (const float*)d_in[2];
  const float* bqkv = (const float*)d_in[3];
  const float* Wproj = (const float*)d_in[4];
  const float* bproj = (const float*)d_in[5];
  float* out = (float*)d_out;

  char* ws = (char*)d_ws;
  bf16_t* xb = (bf16_t*)ws;     ws += (size_t)8192 * 768 * 2;
  bf16_t* wqkvb = (bf16_t*)ws;  ws += (size_t)2304 * 768 * 2;
  bf16_t* wprojb = (bf16_t*)ws; ws += (size_t)768 * 768 * 2;
  bf16_t* Qb = (bf16_t*)ws;     ws += (size_t)192 * 1024 * 32 * 2;
  bf16_t* Kb = (bf16_t*)ws;     ws += (size_t)192 * 1024 * 32 * 2;
  bf16_t* Vtb = (bf16_t*)ws;    ws += (size_t)192 * 1024 * 32 * 2;
  bf16_t* Ob = (bf16_t*)ws;     ws += (size_t)8192 * 768 * 2;

  cvt_f32_bf16<<<(8192 * 768 / 4 + 255) / 256, 256, 0, stream>>>(x, xb, 8192 * 768 / 4);
  cvt_f32_bf16<<<(2304 * 768 / 4 + 255) / 256, 256, 0, stream>>>(Wqkv, wqkvb, 2304 * 768 / 4);
  cvt_f32_bf16<<<(768 * 768 / 4 + 255) / 256, 256, 0, stream>>>(Wproj, wprojb, 768 * 768 / 4);

  gemm_bt<0><<<dim3(64, 18), 256, 0, stream>>>(xb, wqkvb, bqkv, nullptr,
                                               Qb, Kb, Vtb, 8192, 2304, 768);
  attn_flash<<<dim3(16, 192), 256, 0, stream>>>(Qb, Kb, Vtb, rel, Ob);
  gemm_bt<1><<<dim3(64, 6), 256, 0, stream>>>(Ob, wprojb, bproj, out,
                                              nullptr, nullptr, nullptr, 8192, 768, 768);
}